// Round 3
// baseline (1372.293 us; speedup 1.0000x reference)
//
#include <hip/hip_runtime.h>
#include <math.h>

#define NCONST 100
#define NF     16
#define NEDGE  9900   // 100*99
#define BLK    512

// One block per batch element, 512 threads.
// LDS budget ~39 KB -> 4 blocks/CU (32 waves/CU).
// Pr/Ps XOR-swizzled on 16B slots (conflict-free ds_read_b128 at lane-distinct
// rows); their pool is reused for the fo-MLP activations after the edge loop.
// W2/W3 staged in LDS (wave-uniform broadcast reads) to kill the per-edge
// s_load/lgkmcnt storms seen in R2.
__global__ __launch_bounds__(BLK, 8) void convint_fused(
    const float* __restrict__ x,
    const float* __restrict__ bn_g, const float* __restrict__ bn_b,
    const float* __restrict__ bn_m, const float* __restrict__ bn_v,
    const float* __restrict__ frw1, const float* __restrict__ frb1,
    const float* __restrict__ frw2, const float* __restrict__ frb2,
    const float* __restrict__ frw3, const float* __restrict__ frb3,
    const float* __restrict__ fow1, const float* __restrict__ fob1,
    const float* __restrict__ fow2, const float* __restrict__ fob2,
    const float* __restrict__ fow3, const float* __restrict__ fob3,
    const float* __restrict__ fcw1, const float* __restrict__ fcb1,
    const float* __restrict__ fcw2, const float* __restrict__ fcb2,
    float* __restrict__ out)
{
    __shared__ float xbn[NCONST][NF];    // 6.4 KB
    __shared__ float upool[6704];        // 26.8 KB: Pr[100][32]+Ps[100][32]  ->  foh1[100][45]+foh2[100][22]
    __shared__ float agg[NCONST][9];     // 3.6 KB (6 used; 9 coprime to 32)
    __shared__ float w2s[450];           // 1.8 KB
    __shared__ float w3s[90];            // 0.36 KB
    __shared__ float fcin[8];
    __shared__ float hfc[48];
    __shared__ float logits[8];

    float (* const Pr)[32]   = (float (*)[32])upool;
    float (* const Ps)[32]   = (float (*)[32])(upool + 3200);
    float (* const foh1)[45] = (float (*)[45])upool;
    float (* const foh2)[22] = (float (*)[22])(upool + 4500);

    const int b   = blockIdx.x;
    const int tid = threadIdx.x;
    const float* xb = x + (size_t)b * (NCONST * NF);

    // ---- BatchNorm into LDS + weight staging + zero-init ----
    for (int idx = tid; idx < NCONST * NF; idx += BLK) {
        int f = idx & 15;
        float sc = rsqrtf(bn_v[f] + 1e-3f) * bn_g[f];
        xbn[idx >> 4][f] = (xb[idx] - bn_m[f]) * sc + bn_b[f];
    }
    if (tid < 450) w2s[tid] = frw2[tid];
    else if (tid < 450 + 90) w3s[tid - 450] = frw3[tid - 450];
    for (int idx = tid; idx < NCONST * 9; idx += BLK)
        ((float*)agg)[idx] = 0.f;
    if (tid < 8) fcin[tid] = 0.f;
    __syncthreads();

    // ---- Per-node layer-1 projections (swizzled store) ----
    for (int idx = tid; idx < 6000; idx += BLK) {
        int n   = idx / 60;
        int rem = idx - n * 60;
        int sel = (rem >= 30) ? 1 : 0;
        int o   = rem - sel * 30;
        const float* w = frw1 + (sel * 16) * 30 + o;
        float acc = 0.f;
        #pragma unroll
        for (int f = 0; f < 16; ++f) acc = fmaf(xbn[n][f], w[f * 30], acc);
        int col = (((o >> 2) ^ (n & 7)) << 2) + (o & 3);
        if (sel) Ps[n][col] = acc; else Pr[n][col] = acc;
    }
    __syncthreads();

    // ---- Edge MLP + scatter-add ----
    for (int e = tid; e < NEDGE; e += BLK) {
        int s = e / 100;
        int i = e - s * 100;
        int j = i + 1 + s;
        if (j >= 100) j -= 100;

        const float4* pr4 = (const float4*)(&Pr[i][0]);
        const float4* ps4 = (const float4*)(&Ps[j][0]);
        const int mi = i & 7, mj = j & 7;

        float h1[30];
        #pragma unroll
        for (int q = 0; q < 7; ++q) {
            float4 a = pr4[q ^ mi];
            float4 c = ps4[q ^ mj];
            h1[4*q+0] = fmaxf(a.x + c.x + frb1[4*q+0], 0.f);
            h1[4*q+1] = fmaxf(a.y + c.y + frb1[4*q+1], 0.f);
            h1[4*q+2] = fmaxf(a.z + c.z + frb1[4*q+2], 0.f);
            h1[4*q+3] = fmaxf(a.w + c.w + frb1[4*q+3], 0.f);
        }
        {
            float4 a = pr4[7 ^ mi];
            float4 c = ps4[7 ^ mj];
            h1[28] = fmaxf(a.x + c.x + frb1[28], 0.f);
            h1[29] = fmaxf(a.y + c.y + frb1[29], 0.f);
        }

        // h2 = relu(h1 @ W2 + b2) ; W2 from LDS (broadcast)
        float h2[15];
        #pragma unroll
        for (int o = 0; o < 15; ++o) h2[o] = frb2[o];
        #pragma unroll
        for (int k = 0; k < 30; ++k) {
            float hk = h1[k];
            #pragma unroll
            for (int o = 0; o < 15; ++o) h2[o] = fmaf(hk, w2s[k*15+o], h2[o]);
        }
        #pragma unroll
        for (int o = 0; o < 15; ++o) h2[o] = fmaxf(h2[o], 0.f);

        // eff = relu(h2 @ W3 + b3); scatter-add to receiver i
        #pragma unroll
        for (int c = 0; c < 6; ++c) {
            float acc = frb3[c];
            #pragma unroll
            for (int k = 0; k < 15; ++k) acc = fmaf(h2[k], w3s[k*6+c], acc);
            atomicAdd(&agg[i][c], fmaxf(acc, 0.f));
        }
    }
    __syncthreads();

    // ---- fo layer1 (100x45 dot-22); foh1 overlays Pr/Ps (dead) ----
    // NOTE: read xbn/agg BEFORE writing foh1?  xbn/agg are separate buffers; ok.
    for (int idx = tid; idx < NCONST * 45; idx += BLK) {
        int n = idx / 45, o = idx - n * 45;
        float acc = fob1[o];
        #pragma unroll
        for (int k = 0; k < 16; ++k) acc = fmaf(xbn[n][k], fow1[k*45+o], acc);
        #pragma unroll
        for (int k = 0; k < 6; ++k)  acc = fmaf(agg[n][k], fow1[(16+k)*45+o], acc);
        foh1[n][o] = fmaxf(acc, 0.f);
    }
    __syncthreads();

    // ---- fo layer2 (100x22 dot-45) ----
    for (int idx = tid; idx < NCONST * 22; idx += BLK) {
        int n = idx / 22, o = idx - n * 22;
        float acc = fob2[o];
        #pragma unroll
        for (int k = 0; k < 45; ++k) acc = fmaf(foh1[n][k], fow2[k*22+o], acc);
        foh2[n][o] = fmaxf(acc, 0.f);
    }
    __syncthreads();

    // ---- fo layer3 (100x6 dot-22) + sum over nodes ----
    for (int idx = tid; idx < NCONST * 6; idx += BLK) {
        int n = idx / 6, c = idx - n * 6;
        float acc = fob3[c];
        #pragma unroll
        for (int k = 0; k < 22; ++k) acc = fmaf(foh2[n][k], fow3[k*6+c], acc);
        atomicAdd(&fcin[c], fmaxf(acc, 0.f));
    }
    __syncthreads();

    // ---- fc: 6 -> 48 (relu) -> 5 -> softmax ----
    if (tid < 48) {
        float acc = fcb1[tid];
        #pragma unroll
        for (int k = 0; k < 6; ++k) acc = fmaf(fcin[k], fcw1[k*48 + tid], acc);
        hfc[tid] = fmaxf(acc, 0.f);
    }
    __syncthreads();
    if (tid < 5) {
        float acc = fcb2[tid];
        #pragma unroll
        for (int k = 0; k < 48; ++k) acc = fmaf(hfc[k], fcw2[k*5 + tid], acc);
        logits[tid] = acc;
    }
    __syncthreads();
    if (tid == 0) {
        float m = logits[0];
        #pragma unroll
        for (int c = 1; c < 5; ++c) m = fmaxf(m, logits[c]);
        float ex[5], sum = 0.f;
        #pragma unroll
        for (int c = 0; c < 5; ++c) { ex[c] = __expf(logits[c] - m); sum += ex[c]; }
        float inv = 1.f / sum;
        #pragma unroll
        for (int c = 0; c < 5; ++c) out[(size_t)b * 5 + c] = ex[c] * inv;
    }
}

extern "C" void kernel_launch(void* const* d_in, const int* in_sizes, int n_in,
                              void* d_out, int out_size, void* d_ws, size_t ws_size,
                              hipStream_t stream) {
    const float* x     = (const float*)d_in[0];
    const float* bn_g  = (const float*)d_in[1];
    const float* bn_b  = (const float*)d_in[2];
    const float* bn_m  = (const float*)d_in[3];
    const float* bn_v  = (const float*)d_in[4];
    const float* frw1  = (const float*)d_in[5];
    const float* frb1  = (const float*)d_in[6];
    const float* frw2  = (const float*)d_in[7];
    const float* frb2  = (const float*)d_in[8];
    const float* frw3  = (const float*)d_in[9];
    const float* frb3  = (const float*)d_in[10];
    const float* fow1  = (const float*)d_in[11];
    const float* fob1  = (const float*)d_in[12];
    const float* fow2  = (const float*)d_in[13];
    const float* fob2  = (const float*)d_in[14];
    const float* fow3  = (const float*)d_in[15];
    const float* fob3  = (const float*)d_in[16];
    const float* fcw1  = (const float*)d_in[17];
    const float* fcb1  = (const float*)d_in[18];
    const float* fcw2  = (const float*)d_in[19];
    const float* fcb2  = (const float*)d_in[20];

    const int B = in_sizes[0] / (NCONST * NF);   // 512

    convint_fused<<<dim3(B), dim3(BLK), 0, stream>>>(
        x, bn_g, bn_b, bn_m, bn_v,
        frw1, frb1, frw2, frb2, frw3, frb3,
        fow1, fob1, fow2, fob2, fow3, fob3,
        fcw1, fcb1, fcw2, fcb2,
        (float*)d_out);
}

// Round 4
// 894.244 us; speedup vs baseline: 1.5346x; 1.5346x over previous
//
#include <hip/hip_runtime.h>
#include <math.h>

#define NCONST 100
#define NF     16
#define NEDGE  9900   // 100*99
#define BLK    512

// One block per batch element, 512 threads.
// LDS ~38.5 KB -> 4 blocks/CU possible; launch_bounds(512,4) keeps VGPR<=128
// (R2 compiled to 56 naturally -> 8 waves/SIMD schedulable). DO NOT raise the
// min-waves arg: (512,8) forced VGPR=32 and spilled h1/h2 to scratch -> 3 GB
// of HBM traffic per dispatch (R3, 1372 us).
// Pr/Ps XOR-swizzled on 16B slots; pool reused for fo-MLP activations.
// W2/W3 staged in LDS (wave-uniform broadcast reads, no per-edge s_load storm).
__global__ __launch_bounds__(BLK, 4) void convint_fused(
    const float* __restrict__ x,
    const float* __restrict__ bn_g, const float* __restrict__ bn_b,
    const float* __restrict__ bn_m, const float* __restrict__ bn_v,
    const float* __restrict__ frw1, const float* __restrict__ frb1,
    const float* __restrict__ frw2, const float* __restrict__ frb2,
    const float* __restrict__ frw3, const float* __restrict__ frb3,
    const float* __restrict__ fow1, const float* __restrict__ fob1,
    const float* __restrict__ fow2, const float* __restrict__ fob2,
    const float* __restrict__ fow3, const float* __restrict__ fob3,
    const float* __restrict__ fcw1, const float* __restrict__ fcb1,
    const float* __restrict__ fcw2, const float* __restrict__ fcb2,
    float* __restrict__ out)
{
    __shared__ float xbn[NCONST][NF];    // 6.4 KB
    __shared__ float upool[6704];        // 26.8 KB: Pr+Ps -> foh1+foh2
    __shared__ float agg[NCONST][9];     // 3.6 KB (6 used; 9 coprime to 32)
    __shared__ float w2s[450];           // 1.8 KB
    __shared__ float w3s[90];            // 0.36 KB
    __shared__ float fcin[8];
    __shared__ float hfc[48];
    __shared__ float logits[8];

    float (* const Pr)[32]   = (float (*)[32])upool;
    float (* const Ps)[32]   = (float (*)[32])(upool + 3200);
    float (* const foh1)[45] = (float (*)[45])upool;
    float (* const foh2)[22] = (float (*)[22])(upool + 4500);

    const int b   = blockIdx.x;
    const int tid = threadIdx.x;
    const float* xb = x + (size_t)b * (NCONST * NF);

    // ---- BatchNorm into LDS + weight staging + zero-init ----
    for (int idx = tid; idx < NCONST * NF; idx += BLK) {
        int f = idx & 15;
        float sc = rsqrtf(bn_v[f] + 1e-3f) * bn_g[f];
        xbn[idx >> 4][f] = (xb[idx] - bn_m[f]) * sc + bn_b[f];
    }
    if (tid < 450) w2s[tid] = frw2[tid];
    else if (tid < 450 + 90) w3s[tid - 450] = frw3[tid - 450];
    for (int idx = tid; idx < NCONST * 9; idx += BLK)
        ((float*)agg)[idx] = 0.f;
    if (tid < 8) fcin[tid] = 0.f;
    __syncthreads();

    // ---- Per-node layer-1 projections (swizzled store) ----
    for (int idx = tid; idx < 6000; idx += BLK) {
        int n   = idx / 60;
        int rem = idx - n * 60;
        int sel = (rem >= 30) ? 1 : 0;
        int o   = rem - sel * 30;
        const float* w = frw1 + (sel * 16) * 30 + o;
        float acc = 0.f;
        #pragma unroll
        for (int f = 0; f < 16; ++f) acc = fmaf(xbn[n][f], w[f * 30], acc);
        int col = (((o >> 2) ^ (n & 7)) << 2) + (o & 3);
        if (sel) Ps[n][col] = acc; else Pr[n][col] = acc;
    }
    __syncthreads();

    // ---- Edge MLP + scatter-add ----
    for (int e = tid; e < NEDGE; e += BLK) {
        int s = e / 100;
        int i = e - s * 100;
        int j = i + 1 + s;
        if (j >= 100) j -= 100;

        const float4* pr4 = (const float4*)(&Pr[i][0]);
        const float4* ps4 = (const float4*)(&Ps[j][0]);
        const int mi = i & 7, mj = j & 7;

        float h1[30];
        #pragma unroll
        for (int q = 0; q < 7; ++q) {
            float4 a = pr4[q ^ mi];
            float4 c = ps4[q ^ mj];
            h1[4*q+0] = fmaxf(a.x + c.x + frb1[4*q+0], 0.f);
            h1[4*q+1] = fmaxf(a.y + c.y + frb1[4*q+1], 0.f);
            h1[4*q+2] = fmaxf(a.z + c.z + frb1[4*q+2], 0.f);
            h1[4*q+3] = fmaxf(a.w + c.w + frb1[4*q+3], 0.f);
        }
        {
            float4 a = pr4[7 ^ mi];
            float4 c = ps4[7 ^ mj];
            h1[28] = fmaxf(a.x + c.x + frb1[28], 0.f);
            h1[29] = fmaxf(a.y + c.y + frb1[29], 0.f);
        }

        // h2 = relu(h1 @ W2 + b2) ; W2 from LDS (broadcast)
        float h2[15];
        #pragma unroll
        for (int o = 0; o < 15; ++o) h2[o] = frb2[o];
        #pragma unroll
        for (int k = 0; k < 30; ++k) {
            float hk = h1[k];
            #pragma unroll
            for (int o = 0; o < 15; ++o) h2[o] = fmaf(hk, w2s[k*15+o], h2[o]);
        }
        #pragma unroll
        for (int o = 0; o < 15; ++o) h2[o] = fmaxf(h2[o], 0.f);

        // eff = relu(h2 @ W3 + b3); scatter-add to receiver i
        #pragma unroll
        for (int c = 0; c < 6; ++c) {
            float acc = frb3[c];
            #pragma unroll
            for (int k = 0; k < 15; ++k) acc = fmaf(h2[k], w3s[k*6+c], acc);
            atomicAdd(&agg[i][c], fmaxf(acc, 0.f));
        }
    }
    __syncthreads();

    // ---- fo layer1 (100x45 dot-22); foh1 overlays Pr/Ps (dead) ----
    for (int idx = tid; idx < NCONST * 45; idx += BLK) {
        int n = idx / 45, o = idx - n * 45;
        float acc = fob1[o];
        #pragma unroll
        for (int k = 0; k < 16; ++k) acc = fmaf(xbn[n][k], fow1[k*45+o], acc);
        #pragma unroll
        for (int k = 0; k < 6; ++k)  acc = fmaf(agg[n][k], fow1[(16+k)*45+o], acc);
        foh1[n][o] = fmaxf(acc, 0.f);
    }
    __syncthreads();

    // ---- fo layer2 (100x22 dot-45) ----
    for (int idx = tid; idx < NCONST * 22; idx += BLK) {
        int n = idx / 22, o = idx - n * 22;
        float acc = fob2[o];
        #pragma unroll
        for (int k = 0; k < 45; ++k) acc = fmaf(foh1[n][k], fow2[k*22+o], acc);
        foh2[n][o] = fmaxf(acc, 0.f);
    }
    __syncthreads();

    // ---- fo layer3 (100x6 dot-22) + sum over nodes ----
    for (int idx = tid; idx < NCONST * 6; idx += BLK) {
        int n = idx / 6, c = idx - n * 6;
        float acc = fob3[c];
        #pragma unroll
        for (int k = 0; k < 22; ++k) acc = fmaf(foh2[n][k], fow3[k*6+c], acc);
        atomicAdd(&fcin[c], fmaxf(acc, 0.f));
    }
    __syncthreads();

    // ---- fc: 6 -> 48 (relu) -> 5 -> softmax ----
    if (tid < 48) {
        float acc = fcb1[tid];
        #pragma unroll
        for (int k = 0; k < 6; ++k) acc = fmaf(fcin[k], fcw1[k*48 + tid], acc);
        hfc[tid] = fmaxf(acc, 0.f);
    }
    __syncthreads();
    if (tid < 5) {
        float acc = fcb2[tid];
        #pragma unroll
        for (int k = 0; k < 48; ++k) acc = fmaf(hfc[k], fcw2[k*5 + tid], acc);
        logits[tid] = acc;
    }
    __syncthreads();
    if (tid == 0) {
        float m = logits[0];
        #pragma unroll
        for (int c = 1; c < 5; ++c) m = fmaxf(m, logits[c]);
        float ex[5], sum = 0.f;
        #pragma unroll
        for (int c = 0; c < 5; ++c) { ex[c] = __expf(logits[c] - m); sum += ex[c]; }
        float inv = 1.f / sum;
        #pragma unroll
        for (int c = 0; c < 5; ++c) out[(size_t)b * 5 + c] = ex[c] * inv;
    }
}

extern "C" void kernel_launch(void* const* d_in, const int* in_sizes, int n_in,
                              void* d_out, int out_size, void* d_ws, size_t ws_size,
                              hipStream_t stream) {
    const float* x     = (const float*)d_in[0];
    const float* bn_g  = (const float*)d_in[1];
    const float* bn_b  = (const float*)d_in[2];
    const float* bn_m  = (const float*)d_in[3];
    const float* bn_v  = (const float*)d_in[4];
    const float* frw1  = (const float*)d_in[5];
    const float* frb1  = (const float*)d_in[6];
    const float* frw2  = (const float*)d_in[7];
    const float* frb2  = (const float*)d_in[8];
    const float* frw3  = (const float*)d_in[9];
    const float* frb3  = (const float*)d_in[10];
    const float* fow1  = (const float*)d_in[11];
    const float* fob1  = (const float*)d_in[12];
    const float* fow2  = (const float*)d_in[13];
    const float* fob2  = (const float*)d_in[14];
    const float* fow3  = (const float*)d_in[15];
    const float* fob3  = (const float*)d_in[16];
    const float* fcw1  = (const float*)d_in[17];
    const float* fcb1  = (const float*)d_in[18];
    const float* fcw2  = (const float*)d_in[19];
    const float* fcb2  = (const float*)d_in[20];

    const int B = in_sizes[0] / (NCONST * NF);   // 512

    convint_fused<<<dim3(B), dim3(BLK), 0, stream>>>(
        x, bn_g, bn_b, bn_m, bn_v,
        frw1, frb1, frw2, frb2, frw3, frb3,
        fow1, fob1, fow2, fob2, fow3, fob3,
        fcw1, fcb1, fcw2, fcb2,
        (float*)d_out);
}

// Round 5
// 208.484 us; speedup vs baseline: 6.5822x; 4.2893x over previous
//
#include <hip/hip_runtime.h>
#include <math.h>

#define NCONST 100
#define NF     16
#define NEDGE  9900   // 100*99
#define BLK    512
#define NTILE  619    // ceil(9900/16) edges per 16-row MFMA tile

typedef _Float16 f16x8 __attribute__((ext_vector_type(8)));
typedef float    f32x4 __attribute__((ext_vector_type(4)));

// One block per batch element, 512 threads (8 waves).
// Edge MLP via MFMA f16: W2/W3 live in 8 VGPRs/thread as B-fragments (loaded
// once) -- eliminates the per-edge weight-load storm that stalled R2 (scalar
// K$ latency) and spilled R3/R4 (LDS-weight register pressure).
// Pr/Ps stored f16, rows padded to 40 halves (80B: 16B-aligned, 20 words ->
// rows r and r+8 share banks 2-way = free) ; b1 folded into Pr; k=30..39 pad
// zeroed so the K=32 MFMA pad contributes nothing.
// Per-wave h2 transpose buffer: 16x40 f16 rows, same bank-safe layout.
__global__ __launch_bounds__(BLK, 4) void convint_fused(
    const float* __restrict__ x,
    const float* __restrict__ bn_g, const float* __restrict__ bn_b,
    const float* __restrict__ bn_m, const float* __restrict__ bn_v,
    const float* __restrict__ frw1, const float* __restrict__ frb1,
    const float* __restrict__ frw2, const float* __restrict__ frb2,
    const float* __restrict__ frw3, const float* __restrict__ frb3,
    const float* __restrict__ fow1, const float* __restrict__ fob1,
    const float* __restrict__ fow2, const float* __restrict__ fob2,
    const float* __restrict__ fow3, const float* __restrict__ fob3,
    const float* __restrict__ fcw1, const float* __restrict__ fcb1,
    const float* __restrict__ fcw2, const float* __restrict__ fcb2,
    float* __restrict__ out)
{
    __shared__ float xbn[NCONST][NF];   // 6.4 KB
    __shared__ float upool[6704];       // 26.8 KB, multi-use (see below)
    __shared__ float aggF[NCONST * 9];  // 3.6 KB (6 used/row; 9 coprime to 32)
    __shared__ float fcin[8];
    __shared__ float hfc[48];
    __shared__ float logits[8];

    // Phase E (edge) layout of upool:
    _Float16* const Prh = (_Float16*)upool;            // [100][40] f16, 8000 B
    _Float16* const Psh = (_Float16*)(upool + 2000);   // [100][40] f16, 8000 B
    _Float16* const H2B = (_Float16*)(upool + 4000);   // 8 waves x [16][40] f16
    // Phase F (fo) overlay (edge data dead by then):
    float (*const foh1)[45] = (float (*)[45])upool;            // 100x45
    float (*const foh2)[22] = (float (*)[22])(upool + 4500);   // 100x22

    const int b   = blockIdx.x;
    const int tid = threadIdx.x;
    const float* xb = x + (size_t)b * (NCONST * NF);

    // ---- BatchNorm into LDS + zero-init ----
    for (int idx = tid; idx < NCONST * NF; idx += BLK) {
        int f = idx & 15;
        float sc = rsqrtf(bn_v[f] + 1e-3f) * bn_g[f];
        xbn[idx >> 4][f] = (xb[idx] - bn_m[f]) * sc + bn_b[f];
    }
    for (int idx = tid; idx < NCONST * 9; idx += BLK) aggF[idx] = 0.f;
    if (tid < 8) fcin[tid] = 0.f;
    // zero the k-pad (k=30..39) of Prh/Psh
    for (int idx = tid; idx < NCONST * 10; idx += BLK) {
        int n = idx / 10, kk = idx - n * 10;
        Prh[n * 40 + 30 + kk] = (_Float16)0.f;
        Psh[n * 40 + 30 + kk] = (_Float16)0.f;
    }
    __syncthreads();

    // ---- Per-node layer-1 projections -> f16 LDS (b1 folded into Pr) ----
    for (int idx = tid; idx < 6000; idx += BLK) {
        int n   = idx / 60;
        int rem = idx - n * 60;
        int sel = (rem >= 30) ? 1 : 0;
        int o   = rem - sel * 30;
        const float* w = frw1 + (sel * 16) * 30 + o;
        float acc = sel ? 0.f : frb1[o];
        #pragma unroll
        for (int f = 0; f < 16; ++f) acc = fmaf(xbn[n][f], w[f * 30], acc);
        if (sel) Psh[n * 40 + o] = (_Float16)acc;
        else     Prh[n * 40 + o] = (_Float16)acc;
    }
    __syncthreads();

    // ---- Edge phase: per-wave 16-edge MFMA tiles ----
    {
        const int l  = tid & 63;
        const int w  = tid >> 6;      // wave id 0..7
        const int o  = l & 15;        // A-row / C-col index
        const int kb = l >> 4;        // k-block 0..3

        // B-fragments (held in VGPRs for the whole loop):
        f16x8 bf1, bf2;
        #pragma unroll
        for (int m = 0; m < 8; ++m) {
            int k = kb * 8 + m;
            bf1[m] = (k < 30 && o < 15) ? (_Float16)frw2[k * 15 + o] : (_Float16)0.f;
            bf2[m] = (k < 15 && o < 6)  ? (_Float16)frw3[k * 6 + o]  : (_Float16)0.f;
        }
        const float b2l = (o < 15) ? frb2[o] : 0.f;
        const float b3l = (o < 6)  ? frb3[o] : 0.f;
        f32x4 cz; cz[0] = 0.f; cz[1] = 0.f; cz[2] = 0.f; cz[3] = 0.f;

        _Float16* const h2b = H2B + w * 640;   // this wave's [16][40]

        for (int t = w; t < NTILE; t += 8) {
            const int te = t * 16;
            // edge for this lane's A-row
            int e = te + o;
            int s = e / 100;
            int ii = e - s * 100;
            int jj = ii + 1 + s; if (jj >= 100) jj -= 100;   // (wraps to ii on pad rows; reads are safe)

            // A1 = relu(Pr'(i) + Ps(j)) slice, 8 f16
            f16x8 pr = *(const f16x8*)(Prh + ii * 40 + kb * 8);
            f16x8 ps = *(const f16x8*)(Psh + jj * 40 + kb * 8);
            f16x8 h1;
            #pragma unroll
            for (int m = 0; m < 8; ++m) {
                _Float16 v = (_Float16)(pr[m] + ps[m]);
                h1[m] = (v > (_Float16)0.f) ? v : (_Float16)0.f;
            }

            // layer 2: h2pre = h1 @ W2
            f32x4 c1 = __builtin_amdgcn_mfma_f32_16x16x32_f16(h1, bf1, cz, 0, 0, 0);

            // relu+bias, transpose via per-wave LDS bounce
            #pragma unroll
            for (int reg = 0; reg < 4; ++reg) {
                float v = fmaxf(c1[reg] + b2l, 0.f);
                h2b[(kb * 4 + reg) * 40 + o] = (_Float16)v;
            }
            asm volatile("s_waitcnt lgkmcnt(0)" ::: "memory");

            f16x8 a2;
            #pragma unroll
            for (int m = 0; m < 8; ++m) a2[m] = (_Float16)0.f;
            if (kb < 2) a2 = *(const f16x8*)(h2b + o * 40 + kb * 8);

            // layer 3: eff_pre = h2 @ W3
            f32x4 c2 = __builtin_amdgcn_mfma_f32_16x16x32_f16(a2, bf2, cz, 0, 0, 0);

            // scatter-add to receivers
            const int tem = te % 100;   // wave-uniform
            #pragma unroll
            for (int reg = 0; reg < 4; ++reg) {
                int row = kb * 4 + reg;
                if (o < 6 && (te + row) < NEDGE) {
                    int ir = tem + row; if (ir >= 100) ir -= 100;
                    atomicAdd(&aggF[ir * 9 + o], fmaxf(c2[reg] + b3l, 0.f));
                }
            }
        }
    }
    __syncthreads();

    // ---- fo layer1 (100x45 dot-22); foh1 overlays dead edge buffers ----
    for (int idx = tid; idx < NCONST * 45; idx += BLK) {
        int n = idx / 45, o = idx - n * 45;
        float acc = fob1[o];
        #pragma unroll
        for (int k = 0; k < 16; ++k) acc = fmaf(xbn[n][k], fow1[k*45+o], acc);
        #pragma unroll
        for (int k = 0; k < 6; ++k)  acc = fmaf(aggF[n*9+k], fow1[(16+k)*45+o], acc);
        foh1[n][o] = fmaxf(acc, 0.f);
    }
    __syncthreads();

    // ---- fo layer2 (100x22 dot-45) ----
    for (int idx = tid; idx < NCONST * 22; idx += BLK) {
        int n = idx / 22, o = idx - n * 22;
        float acc = fob2[o];
        #pragma unroll
        for (int k = 0; k < 45; ++k) acc = fmaf(foh1[n][k], fow2[k*22+o], acc);
        foh2[n][o] = fmaxf(acc, 0.f);
    }
    __syncthreads();

    // ---- fo layer3 (100x6 dot-22) + sum over nodes ----
    for (int idx = tid; idx < NCONST * 6; idx += BLK) {
        int n = idx / 6, c = idx - n * 6;
        float acc = fob3[c];
        #pragma unroll
        for (int k = 0; k < 22; ++k) acc = fmaf(foh2[n][k], fow3[k*6+c], acc);
        atomicAdd(&fcin[c], fmaxf(acc, 0.f));
    }
    __syncthreads();

    // ---- fc: 6 -> 48 (relu) -> 5 -> softmax ----
    if (tid < 48) {
        float acc = fcb1[tid];
        #pragma unroll
        for (int k = 0; k < 6; ++k) acc = fmaf(fcin[k], fcw1[k*48 + tid], acc);
        hfc[tid] = fmaxf(acc, 0.f);
    }
    __syncthreads();
    if (tid < 5) {
        float acc = fcb2[tid];
        #pragma unroll
        for (int k = 0; k < 48; ++k) acc = fmaf(hfc[k], fcw2[k*5 + tid], acc);
        logits[tid] = acc;
    }
    __syncthreads();
    if (tid == 0) {
        float m = logits[0];
        #pragma unroll
        for (int c = 1; c < 5; ++c) m = fmaxf(m, logits[c]);
        float ex[5], sum = 0.f;
        #pragma unroll
        for (int c = 0; c < 5; ++c) { ex[c] = __expf(logits[c] - m); sum += ex[c]; }
        float inv = 1.f / sum;
        #pragma unroll
        for (int c = 0; c < 5; ++c) out[(size_t)b * 5 + c] = ex[c] * inv;
    }
}

extern "C" void kernel_launch(void* const* d_in, const int* in_sizes, int n_in,
                              void* d_out, int out_size, void* d_ws, size_t ws_size,
                              hipStream_t stream) {
    const float* x     = (const float*)d_in[0];
    const float* bn_g  = (const float*)d_in[1];
    const float* bn_b  = (const float*)d_in[2];
    const float* bn_m  = (const float*)d_in[3];
    const float* bn_v  = (const float*)d_in[4];
    const float* frw1  = (const float*)d_in[5];
    const float* frb1  = (const float*)d_in[6];
    const float* frw2  = (const float*)d_in[7];
    const float* frb2  = (const float*)d_in[8];
    const float* frw3  = (const float*)d_in[9];
    const float* frb3  = (const float*)d_in[10];
    const float* fow1  = (const float*)d_in[11];
    const float* fob1  = (const float*)d_in[12];
    const float* fow2  = (const float*)d_in[13];
    const float* fob2  = (const float*)d_in[14];
    const float* fow3  = (const float*)d_in[15];
    const float* fob3  = (const float*)d_in[16];
    const float* fcw1  = (const float*)d_in[17];
    const float* fcb1  = (const float*)d_in[18];
    const float* fcw2  = (const float*)d_in[19];
    const float* fcb2  = (const float*)d_in[20];

    const int B = in_sizes[0] / (NCONST * NF);   // 512

    convint_fused<<<dim3(B), dim3(BLK), 0, stream>>>(
        x, bn_g, bn_b, bn_m, bn_v,
        frw1, frb1, frw2, frb2, frw3, frb3,
        fow1, fob1, fow2, fob2, fow3, fob3,
        fcw1, fcb1, fcw2, fcb2,
        (float*)d_out);
}

// Round 6
// 68.634 us; speedup vs baseline: 19.9944x; 3.0376x over previous
//
#include <hip/hip_runtime.h>
#include <math.h>

#define NCONST 100
#define NF     16
#define BLK    1024
#define NWAVES 16

typedef _Float16 f16x8 __attribute__((ext_vector_type(8)));
typedef float    f32x4 __attribute__((ext_vector_type(4)));

// One block per batch element, 1024 threads (16 waves).
// Edge phase: tile = (receiver i, 16 senders). Wave owns receiver -> no
// atomics, no scatter; layer-3 accumulates in registers across the 7 tiles.
// MFMA1 computed swapped (D[o2, edge]) so each lane holds its edge's h2 row;
// 4 ds_bpermute redistribute packed-f16 h2 into the MFMA2 A-fragment --
// no LDS bounce, no lgkmcnt(0) barrier, loop is compiler-pipelineable.
// (A-frag: row=l&15, k=(l>>4)*8+m; C/D: col=l&15, row=(l>>4)*4+reg --
// hardware-verified by R5's passing bounce kernel.)
__global__ __launch_bounds__(BLK, 4) void convint_fused(
    const float* __restrict__ x,
    const float* __restrict__ bn_g, const float* __restrict__ bn_b,
    const float* __restrict__ bn_m, const float* __restrict__ bn_v,
    const float* __restrict__ frw1, const float* __restrict__ frb1,
    const float* __restrict__ frw2, const float* __restrict__ frb2,
    const float* __restrict__ frw3, const float* __restrict__ frb3,
    const float* __restrict__ fow1, const float* __restrict__ fob1,
    const float* __restrict__ fow2, const float* __restrict__ fob2,
    const float* __restrict__ fow3, const float* __restrict__ fob3,
    const float* __restrict__ fcw1, const float* __restrict__ fcb1,
    const float* __restrict__ fcw2, const float* __restrict__ fcb2,
    float* __restrict__ out)
{
    __shared__ float xbn[NCONST][NF];   // 6.4 KB
    __shared__ float upool[6704];       // 26.8 KB multi-use
    __shared__ float aggF[NCONST * 9];  // 3.6 KB (6 used/row)
    __shared__ float fcin[8];
    __shared__ float hfc[48];
    __shared__ float logits[8];

    // Edge-phase layout: Pr/Ps f16, rows padded to 40 halves (80 B).
    _Float16* const Prh = (_Float16*)upool;            // [100][40]
    _Float16* const Psh = (_Float16*)(upool + 2000);   // [100][40]
    // fo-phase overlay (edge data dead):
    float (*const foh1)[45] = (float (*)[45])upool;            // 100x45
    float (*const foh2)[22] = (float (*)[22])(upool + 4500);   // 100x22

    const int b   = blockIdx.x;
    const int tid = threadIdx.x;
    const float* xb = x + (size_t)b * (NCONST * NF);

    // ---- BatchNorm into LDS + init ----
    for (int idx = tid; idx < NCONST * NF; idx += BLK) {
        int f = idx & 15;
        float sc = rsqrtf(bn_v[f] + 1e-3f) * bn_g[f];
        xbn[idx >> 4][f] = (xb[idx] - bn_m[f]) * sc + bn_b[f];
    }
    if (tid < 8) fcin[tid] = 0.f;
    for (int idx = tid; idx < NCONST * 10; idx += BLK) {   // zero k-pad 30..39
        int n = idx / 10, kk = idx - n * 10;
        Prh[n * 40 + 30 + kk] = (_Float16)0.f;
        Psh[n * 40 + 30 + kk] = (_Float16)0.f;
    }
    __syncthreads();

    // ---- Per-node layer-1 projections -> f16 LDS (b1 folded into Pr) ----
    for (int idx = tid; idx < 6000; idx += BLK) {
        int n   = idx / 60;
        int rem = idx - n * 60;
        int sel = (rem >= 30) ? 1 : 0;
        int o   = rem - sel * 30;
        const float* w = frw1 + (sel * 16) * 30 + o;
        float acc = sel ? 0.f : frb1[o];
        #pragma unroll
        for (int f = 0; f < 16; ++f) acc = fmaf(xbn[n][f], w[f * 30], acc);
        if (sel) Psh[n * 40 + o] = (_Float16)acc;
        else     Prh[n * 40 + o] = (_Float16)acc;
    }
    __syncthreads();

    // ---- Edge phase: per-wave receivers, 7 sender-tiles each ----
    {
        const int l  = tid & 63;
        const int wv = tid >> 6;      // wave 0..15
        const int o  = l & 15;
        const int kb = l >> 4;        // 0..3

        // Weight fragments (VGPR-resident for the whole loop)
        f16x8 bf1, bf2;
        #pragma unroll
        for (int m = 0; m < 8; ++m) {
            int k = kb * 8 + m;
            bf1[m] = (k < 30 && o < 15) ? (_Float16)frw2[k * 15 + o] : (_Float16)0.f;
            bf2[m] = (k < 15 && o < 6)  ? (_Float16)frw3[k * 6 + o]  : (_Float16)0.f;
        }
        float b2r[4];
        #pragma unroll
        for (int r = 0; r < 4; ++r) {
            int o2 = kb * 4 + r;
            b2r[r] = (o2 < 15) ? frb2[o2] : 0.f;
        }
        const float b3l = (o < 6) ? frb3[o] : 0.f;
        // bpermute source-lane byte indices (constant per lane)
        const int kb1 = kb & 1;
        const int perm0 = (o + 16 * (((kb1 * 8) + 0) >> 2)) << 2;
        const int perm1 = (o + 16 * (((kb1 * 8) + 2) >> 2)) << 2;
        const int perm2 = (o + 16 * (((kb1 * 8) + 4) >> 2)) << 2;
        const int perm3 = (o + 16 * (((kb1 * 8) + 6) >> 2)) << 2;
        f32x4 cz; cz[0] = 0.f; cz[1] = 0.f; cz[2] = 0.f; cz[3] = 0.f;

        for (int i = wv; i < NCONST; i += NWAVES) {
            const f16x8 pri = *(const f16x8*)(Prh + i * 40 + kb * 8);  // broadcast, reused 7 tiles
            f32x4 racc = cz;
            #pragma unroll 1
            for (int tb = 0; tb < 7; ++tb) {
                int si = tb * 16 + o;           // sender index 0..111 (pad >=99)
                int j  = i + 1 + si;            // <= 211
                if (j >= 100) j -= 100;
                if (j >= 100) j -= 100;
                f16x8 ps = *(const f16x8*)(Psh + j * 40 + kb * 8);
                f16x8 h1;
                #pragma unroll
                for (int m = 0; m < 8; ++m) {
                    _Float16 v = (_Float16)(pri[m] + ps[m]);
                    h1[m] = (v > (_Float16)0.f) ? v : (_Float16)0.f;
                }
                // MFMA1 swapped: D[o2, edge]; lane: col=edge=l&15, rows o2=kb*4+reg
                f32x4 c1 = __builtin_amdgcn_mfma_f32_16x16x32_f16(bf1, h1, cz, 0, 0, 0);
                // h2 = relu(c1 + b2), packed to 2 f16-pair words
                union { unsigned u; _Float16 h[2]; } pk0, pk1;
                pk0.h[0] = (_Float16)fmaxf(c1[0] + b2r[0], 0.f);
                pk0.h[1] = (_Float16)fmaxf(c1[1] + b2r[1], 0.f);
                pk1.h[0] = (_Float16)fmaxf(c1[2] + b2r[2], 0.f);
                pk1.h[1] = (_Float16)fmaxf(c1[3] + b2r[3], 0.f);
                // redistribute to MFMA2 A-frag: a2[m] = h2[edge=l&15, k2=kb*8+m]
                union { int w[4]; f16x8 v; } a2u;
                a2u.w[0] = __builtin_amdgcn_ds_bpermute(perm0, (int)pk0.u);
                a2u.w[1] = __builtin_amdgcn_ds_bpermute(perm1, (int)pk1.u);
                a2u.w[2] = __builtin_amdgcn_ds_bpermute(perm2, (int)pk0.u);
                a2u.w[3] = __builtin_amdgcn_ds_bpermute(perm3, (int)pk1.u);
                // (kb>=2 lanes read junk; bf2=0 there zeroes the product)
                f32x4 c2 = __builtin_amdgcn_mfma_f32_16x16x32_f16(a2u.v, bf2, cz, 0, 0, 0);
                // accumulate relu'd effects, masking pad senders (si>=99)
                #pragma unroll
                for (int r = 0; r < 4; ++r) {
                    int row = kb * 4 + r;
                    float v = fmaxf(c2[r] + b3l, 0.f);
                    racc[r] += (tb * 16 + row < 99) ? v : 0.f;
                }
            }
            // reduce over the 16 tile-rows: regs then kb-groups
            float s2 = racc[0] + racc[1] + racc[2] + racc[3];
            s2 += __shfl_xor(s2, 16);
            s2 += __shfl_xor(s2, 32);
            if (kb == 0 && o < 6) aggF[i * 9 + o] = s2;   // exclusive owner: plain store
        }
    }
    __syncthreads();

    // ---- fo layer1 (100x45 dot-22); foh1 overlays dead edge buffers ----
    for (int idx = tid; idx < NCONST * 45; idx += BLK) {
        int n = idx / 45, o = idx - n * 45;
        float acc = fob1[o];
        #pragma unroll
        for (int k = 0; k < 16; ++k) acc = fmaf(xbn[n][k], fow1[k*45+o], acc);
        #pragma unroll
        for (int k = 0; k < 6; ++k)  acc = fmaf(aggF[n*9+k], fow1[(16+k)*45+o], acc);
        foh1[n][o] = fmaxf(acc, 0.f);
    }
    __syncthreads();

    // ---- fo layer2 (100x22 dot-45) ----
    for (int idx = tid; idx < NCONST * 22; idx += BLK) {
        int n = idx / 22, o = idx - n * 22;
        float acc = fob2[o];
        #pragma unroll
        for (int k = 0; k < 45; ++k) acc = fmaf(foh1[n][k], fow2[k*22+o], acc);
        foh2[n][o] = fmaxf(acc, 0.f);
    }
    __syncthreads();

    // ---- fo layer3 (100x6 dot-22) + sum over nodes ----
    for (int idx = tid; idx < NCONST * 6; idx += BLK) {
        int n = idx / 6, c = idx - n * 6;
        float acc = fob3[c];
        #pragma unroll
        for (int k = 0; k < 22; ++k) acc = fmaf(foh2[n][k], fow3[k*6+c], acc);
        atomicAdd(&fcin[c], fmaxf(acc, 0.f));
    }
    __syncthreads();

    // ---- fc: 6 -> 48 (relu) -> 5 -> softmax ----
    if (tid < 48) {
        float acc = fcb1[tid];
        #pragma unroll
        for (int k = 0; k < 6; ++k) acc = fmaf(fcin[k], fcw1[k*48 + tid], acc);
        hfc[tid] = fmaxf(acc, 0.f);
    }
    __syncthreads();
    if (tid < 5) {
        float acc = fcb2[tid];
        #pragma unroll
        for (int k = 0; k < 48; ++k) acc = fmaf(hfc[k], fcw2[k*5 + tid], acc);
        logits[tid] = acc;
    }
    __syncthreads();
    if (tid == 0) {
        float m = logits[0];
        #pragma unroll
        for (int c = 1; c < 5; ++c) m = fmaxf(m, logits[c]);
        float ex[5], sum = 0.f;
        #pragma unroll
        for (int c = 0; c < 5; ++c) { ex[c] = __expf(logits[c] - m); sum += ex[c]; }
        float inv = 1.f / sum;
        #pragma unroll
        for (int c = 0; c < 5; ++c) out[(size_t)b * 5 + c] = ex[c] * inv;
    }
}

extern "C" void kernel_launch(void* const* d_in, const int* in_sizes, int n_in,
                              void* d_out, int out_size, void* d_ws, size_t ws_size,
                              hipStream_t stream) {
    const float* x     = (const float*)d_in[0];
    const float* bn_g  = (const float*)d_in[1];
    const float* bn_b  = (const float*)d_in[2];
    const float* bn_m  = (const float*)d_in[3];
    const float* bn_v  = (const float*)d_in[4];
    const float* frw1  = (const float*)d_in[5];
    const float* frb1  = (const float*)d_in[6];
    const float* frw2  = (const float*)d_in[7];
    const float* frb2  = (const float*)d_in[8];
    const float* frw3  = (const float*)d_in[9];
    const float* frb3  = (const float*)d_in[10];
    const float* fow1  = (const float*)d_in[11];
    const float* fob1  = (const float*)d_in[12];
    const float* fow2  = (const float*)d_in[13];
    const float* fob2  = (const float*)d_in[14];
    const float* fow3  = (const float*)d_in[15];
    const float* fob3  = (const float*)d_in[16];
    const float* fcw1  = (const float*)d_in[17];
    const float* fcb1  = (const float*)d_in[18];
    const float* fcw2  = (const float*)d_in[19];
    const float* fcb2  = (const float*)d_in[20];

    const int B = in_sizes[0] / (NCONST * NF);   // 512

    convint_fused<<<dim3(B), dim3(BLK), 0, stream>>>(
        x, bn_g, bn_b, bn_m, bn_v,
        frw1, frb1, frw2, frb2, frw3, frb3,
        fow1, fob1, fow2, fob2, fow3, fob3,
        fcw1, fcb1, fcw2, fcb2,
        (float*)d_out);
}

// Round 7
// 68.303 us; speedup vs baseline: 20.0914x; 1.0049x over previous
//
#include <hip/hip_runtime.h>
#include <math.h>

#define NCONST 100
#define NF     16
#define BLK    1024
#define NWAVES 16

typedef _Float16 f16x8 __attribute__((ext_vector_type(8)));
typedef _Float16 f16x4 __attribute__((ext_vector_type(4)));
typedef _Float16 f16x2 __attribute__((ext_vector_type(2)));
typedef float    f32x4 __attribute__((ext_vector_type(4)));

// One block per batch element, 1024 threads (16 waves), 2 blocks/CU.
// Edge phase: wave owns receiver; MFMA1 swapped + 4 ds_bpermute + MFMA2;
// layer-3 accumulates in registers, one plain store per receiver (no atomics).
// DS-pipe is the bottleneck (R6 accounting): all small-GEMM phases now use
// float4/b64 LDS accesses instead of scalars.
// launch_bounds(1024,8) pins VGPR<=64 so 2 blocks/CU always fit; R3 showed
// over-constraining causes scratch spill -> watch FETCH_SIZE for ~1.7MB.
__global__ __launch_bounds__(BLK, 8) void convint_fused(
    const float* __restrict__ x,
    const float* __restrict__ bn_g, const float* __restrict__ bn_b,
    const float* __restrict__ bn_m, const float* __restrict__ bn_v,
    const float* __restrict__ frw1, const float* __restrict__ frb1,
    const float* __restrict__ frw2, const float* __restrict__ frb2,
    const float* __restrict__ frw3, const float* __restrict__ frb3,
    const float* __restrict__ fow1, const float* __restrict__ fob1,
    const float* __restrict__ fow2, const float* __restrict__ fob2,
    const float* __restrict__ fow3, const float* __restrict__ fob3,
    const float* __restrict__ fcw1, const float* __restrict__ fcb1,
    const float* __restrict__ fcw2, const float* __restrict__ fcb2,
    float* __restrict__ out)
{
    __shared__ float xbn[NCONST][NF];   // 6.4 KB
    __shared__ float upool[7200];       // 28.8 KB multi-use
    __shared__ float aggF[NCONST * 8];  // 3.2 KB (6 used/row, 32B rows)
    __shared__ float fcin[8];
    __shared__ float hfc[48];
    __shared__ float logits[8];

    // Edge-phase layout: Pr/Ps f16, rows padded to 40 halves (80 B).
    _Float16* const Prh = (_Float16*)upool;            // [100][40]
    _Float16* const Psh = (_Float16*)(upool + 2000);   // [100][40]
    // fo-phase overlay (edge data dead by then):
    float (*const foh1)[48] = (float (*)[48])upool;            // 100x48 (45 used)
    float (*const foh2)[24] = (float (*)[24])(upool + 4800);   // 100x24 (22 used)

    const int b   = blockIdx.x;
    const int tid = threadIdx.x;
    const float* xb = x + (size_t)b * (NCONST * NF);

    // ---- BatchNorm into LDS + init ----
    for (int idx = tid; idx < NCONST * NF; idx += BLK) {
        int f = idx & 15;
        float sc = rsqrtf(bn_v[f] + 1e-3f) * bn_g[f];
        xbn[idx >> 4][f] = (xb[idx] - bn_m[f]) * sc + bn_b[f];
    }
    if (tid < 8) fcin[tid] = 0.f;
    for (int idx = tid; idx < NCONST * 10; idx += BLK) {   // zero k-pad 30..39
        int n = idx / 10, kk = idx - n * 10;
        Prh[n * 40 + 30 + kk] = (_Float16)0.f;
        Psh[n * 40 + 30 + kk] = (_Float16)0.f;
    }
    __syncthreads();

    // ---- Per-node layer-1 projections -> f16 LDS (b1 folded into Pr) ----
    // item = (n, sel, o-quad): 100*2*8 = 1600 items, 4 outputs each.
    for (int idx = tid; idx < 1600; idx += BLK) {
        int n   = idx >> 4;
        int rem = idx & 15;
        int sel = rem >> 3;
        int oq  = rem & 7;
        int o0  = oq * 4;

        float xs[16];
        {
            const float4* xv = (const float4*)(&xbn[n][0]);
            float4 x0 = xv[0], x1 = xv[1], x2 = xv[2], x3 = xv[3];
            xs[0]=x0.x; xs[1]=x0.y; xs[2]=x0.z; xs[3]=x0.w;
            xs[4]=x1.x; xs[5]=x1.y; xs[6]=x1.z; xs[7]=x1.w;
            xs[8]=x2.x; xs[9]=x2.y; xs[10]=x2.z; xs[11]=x2.w;
            xs[12]=x3.x; xs[13]=x3.y; xs[14]=x3.z; xs[15]=x3.w;
        }
        float acc0 = sel ? 0.f : frb1[o0 + 0];
        float acc1 = sel ? 0.f : frb1[o0 + 1];
        float acc2 = (!sel && oq < 7) ? frb1[o0 + 2] : 0.f;
        float acc3 = (!sel && oq < 7) ? frb1[o0 + 3] : 0.f;
        const int wcol2 = (oq < 7) ? o0 + 2 : 28;   // clamp keeps loads in-bounds
        const float* wbase = frw1 + (sel ? 16 * 30 : 0);
        #pragma unroll
        for (int f = 0; f < 16; ++f) {
            const float* wr = wbase + f * 30;
            float2 wa = *(const float2*)(wr + o0);
            float2 wb = *(const float2*)(wr + wcol2);
            acc0 = fmaf(xs[f], wa.x, acc0);
            acc1 = fmaf(xs[f], wa.y, acc1);
            acc2 = fmaf(xs[f], wb.x, acc2);
            acc3 = fmaf(xs[f], wb.y, acc3);
        }
        _Float16* dst = (sel ? Psh : Prh) + n * 40 + o0;
        if (oq < 7) {
            f16x4 hv;
            hv[0] = (_Float16)acc0; hv[1] = (_Float16)acc1;
            hv[2] = (_Float16)acc2; hv[3] = (_Float16)acc3;
            *(f16x4*)dst = hv;
        } else {
            f16x2 hv;
            hv[0] = (_Float16)acc0; hv[1] = (_Float16)acc1;
            *(f16x2*)dst = hv;
        }
    }
    __syncthreads();

    // ---- Edge phase: per-wave receivers, 7 sender-tiles each ----
    {
        const int l  = tid & 63;
        const int wv = tid >> 6;      // wave 0..15
        const int o  = l & 15;
        const int kb = l >> 4;        // 0..3

        // Weight fragments (VGPR-resident for the whole loop)
        f16x8 bf1, bf2;
        #pragma unroll
        for (int m = 0; m < 8; ++m) {
            int k = kb * 8 + m;
            bf1[m] = (k < 30 && o < 15) ? (_Float16)frw2[k * 15 + o] : (_Float16)0.f;
            bf2[m] = (k < 15 && o < 6)  ? (_Float16)frw3[k * 6 + o]  : (_Float16)0.f;
        }
        float b2r[4];
        #pragma unroll
        for (int r = 0; r < 4; ++r) {
            int o2 = kb * 4 + r;
            b2r[r] = (o2 < 15) ? frb2[o2] : 0.f;
        }
        const float b3l = (o < 6) ? frb3[o] : 0.f;
        // bpermute source-lane byte indices (constant per lane)
        const int kb1 = kb & 1;
        const int perm0 = (o + 16 * (((kb1 * 8) + 0) >> 2)) << 2;
        const int perm1 = (o + 16 * (((kb1 * 8) + 2) >> 2)) << 2;
        const int perm2 = (o + 16 * (((kb1 * 8) + 4) >> 2)) << 2;
        const int perm3 = (o + 16 * (((kb1 * 8) + 6) >> 2)) << 2;
        f32x4 cz; cz[0] = 0.f; cz[1] = 0.f; cz[2] = 0.f; cz[3] = 0.f;

        for (int i = wv; i < NCONST; i += NWAVES) {
            const f16x8 pri = *(const f16x8*)(Prh + i * 40 + kb * 8);
            f32x4 racc = cz;
            #pragma unroll 2
            for (int tb = 0; tb < 7; ++tb) {
                int si = tb * 16 + o;           // sender slot (pad >= 99)
                int j  = i + 1 + si;
                if (j >= 100) j -= 100;
                if (j >= 100) j -= 100;
                f16x8 ps = *(const f16x8*)(Psh + j * 40 + kb * 8);
                f16x8 v = pri + ps;
                f16x8 h1;
                #pragma unroll
                for (int m = 0; m < 8; ++m)
                    h1[m] = (v[m] > (_Float16)0.f) ? v[m] : (_Float16)0.f;

                // MFMA1 swapped: lane holds h2[edge=o][o2=kb*4+r]
                f32x4 c1 = __builtin_amdgcn_mfma_f32_16x16x32_f16(bf1, h1, cz, 0, 0, 0);
                union { unsigned u; _Float16 h[2]; } pk0, pk1;
                pk0.h[0] = (_Float16)fmaxf(c1[0] + b2r[0], 0.f);
                pk0.h[1] = (_Float16)fmaxf(c1[1] + b2r[1], 0.f);
                pk1.h[0] = (_Float16)fmaxf(c1[2] + b2r[2], 0.f);
                pk1.h[1] = (_Float16)fmaxf(c1[3] + b2r[3], 0.f);
                // redistribute to MFMA2 A-frag
                union { int w[4]; f16x8 v; } a2u;
                a2u.w[0] = __builtin_amdgcn_ds_bpermute(perm0, (int)pk0.u);
                a2u.w[1] = __builtin_amdgcn_ds_bpermute(perm1, (int)pk1.u);
                a2u.w[2] = __builtin_amdgcn_ds_bpermute(perm2, (int)pk0.u);
                a2u.w[3] = __builtin_amdgcn_ds_bpermute(perm3, (int)pk1.u);
                f32x4 c2 = __builtin_amdgcn_mfma_f32_16x16x32_f16(a2u.v, bf2, cz, 0, 0, 0);
                #pragma unroll
                for (int r = 0; r < 4; ++r) {
                    int row = kb * 4 + r;
                    float vv = fmaxf(c2[r] + b3l, 0.f);
                    racc[r] += (tb * 16 + row < 99) ? vv : 0.f;
                }
            }
            float s2 = racc[0] + racc[1] + racc[2] + racc[3];
            s2 += __shfl_xor(s2, 16);
            s2 += __shfl_xor(s2, 32);
            if (kb == 0 && o < 6) aggF[i * 8 + o] = s2;   // exclusive owner
        }
    }
    __syncthreads();

    // ---- fo layer1 (100x45 dot-22), float4 LDS reads ----
    for (int idx = tid; idx < NCONST * 45; idx += BLK) {
        int n = idx / 45, o = idx - n * 45;
        float acc = fob1[o];
        const float4* xv = (const float4*)(&xbn[n][0]);
        #pragma unroll
        for (int q = 0; q < 4; ++q) {
            float4 xq = xv[q];
            acc = fmaf(xq.x, fow1[(4*q+0)*45 + o], acc);
            acc = fmaf(xq.y, fow1[(4*q+1)*45 + o], acc);
            acc = fmaf(xq.z, fow1[(4*q+2)*45 + o], acc);
            acc = fmaf(xq.w, fow1[(4*q+3)*45 + o], acc);
        }
        const float4 a0 = *(const float4*)(&aggF[n * 8]);
        const float2 a1 = *(const float2*)(&aggF[n * 8 + 4]);
        acc = fmaf(a0.x, fow1[16*45 + o], acc);
        acc = fmaf(a0.y, fow1[17*45 + o], acc);
        acc = fmaf(a0.z, fow1[18*45 + o], acc);
        acc = fmaf(a0.w, fow1[19*45 + o], acc);
        acc = fmaf(a1.x, fow1[20*45 + o], acc);
        acc = fmaf(a1.y, fow1[21*45 + o], acc);
        foh1[n][o] = fmaxf(acc, 0.f);
    }
    __syncthreads();

    // ---- fo layer2 (100x22 dot-45), float4 LDS reads ----
    for (int idx = tid; idx < NCONST * 22; idx += BLK) {
        int n = idx / 22, o = idx - n * 22;
        float acc = fob2[o];
        const float4* hv = (const float4*)(&foh1[n][0]);
        #pragma unroll
        for (int q = 0; q < 11; ++q) {
            float4 h4 = hv[q];
            acc = fmaf(h4.x, fow2[(4*q+0)*22 + o], acc);
            acc = fmaf(h4.y, fow2[(4*q+1)*22 + o], acc);
            acc = fmaf(h4.z, fow2[(4*q+2)*22 + o], acc);
            acc = fmaf(h4.w, fow2[(4*q+3)*22 + o], acc);
        }
        acc = fmaf(foh1[n][44], fow2[44*22 + o], acc);
        foh2[n][o] = fmaxf(acc, 0.f);
    }
    __syncthreads();

    // ---- fo layer3 (100x6 dot-22) + sum over nodes ----
    for (int idx = tid; idx < NCONST * 6; idx += BLK) {
        int n = idx / 6, c = idx - n * 6;
        float acc = fob3[c];
        const float4* hv = (const float4*)(&foh2[n][0]);
        #pragma unroll
        for (int q = 0; q < 5; ++q) {
            float4 h4 = hv[q];
            acc = fmaf(h4.x, fow3[(4*q+0)*6 + c], acc);
            acc = fmaf(h4.y, fow3[(4*q+1)*6 + c], acc);
            acc = fmaf(h4.z, fow3[(4*q+2)*6 + c], acc);
            acc = fmaf(h4.w, fow3[(4*q+3)*6 + c], acc);
        }
        acc = fmaf(foh2[n][20], fow3[20*6 + c], acc);
        acc = fmaf(foh2[n][21], fow3[21*6 + c], acc);
        atomicAdd(&fcin[c], fmaxf(acc, 0.f));
    }
    __syncthreads();

    // ---- fc: 6 -> 48 (relu) -> 5 -> softmax ----
    if (tid < 48) {
        float acc = fcb1[tid];
        #pragma unroll
        for (int k = 0; k < 6; ++k) acc = fmaf(fcin[k], fcw1[k*48 + tid], acc);
        hfc[tid] = fmaxf(acc, 0.f);
    }
    __syncthreads();
    if (tid < 5) {
        float acc = fcb2[tid];
        #pragma unroll
        for (int k = 0; k < 48; ++k) acc = fmaf(hfc[k], fcw2[k*5 + tid], acc);
        logits[tid] = acc;
    }
    __syncthreads();
    if (tid == 0) {
        float m = logits[0];
        #pragma unroll
        for (int c = 1; c < 5; ++c) m = fmaxf(m, logits[c]);
        float ex[5], sum = 0.f;
        #pragma unroll
        for (int c = 0; c < 5; ++c) { ex[c] = __expf(logits[c] - m); sum += ex[c]; }
        float inv = 1.f / sum;
        #pragma unroll
        for (int c = 0; c < 5; ++c) out[(size_t)b * 5 + c] = ex[c] * inv;
    }
}

extern "C" void kernel_launch(void* const* d_in, const int* in_sizes, int n_in,
                              void* d_out, int out_size, void* d_ws, size_t ws_size,
                              hipStream_t stream) {
    const float* x     = (const float*)d_in[0];
    const float* bn_g  = (const float*)d_in[1];
    const float* bn_b  = (const float*)d_in[2];
    const float* bn_m  = (const float*)d_in[3];
    const float* bn_v  = (const float*)d_in[4];
    const float* frw1  = (const float*)d_in[5];
    const float* frb1  = (const float*)d_in[6];
    const float* frw2  = (const float*)d_in[7];
    const float* frb2  = (const float*)d_in[8];
    const float* frw3  = (const float*)d_in[9];
    const float* frb3  = (const float*)d_in[10];
    const float* fow1  = (const float*)d_in[11];
    const float* fob1  = (const float*)d_in[12];
    const float* fow2  = (const float*)d_in[13];
    const float* fob2  = (const float*)d_in[14];
    const float* fow3  = (const float*)d_in[15];
    const float* fob3  = (const float*)d_in[16];
    const float* fcw1  = (const float*)d_in[17];
    const float* fcb1  = (const float*)d_in[18];
    const float* fcw2  = (const float*)d_in[19];
    const float* fcb2  = (const float*)d_in[20];

    const int B = in_sizes[0] / (NCONST * NF);   // 512

    convint_fused<<<dim3(B), dim3(BLK), 0, stream>>>(
        x, bn_g, bn_b, bn_m, bn_v,
        frw1, frb1, frw2, frb2, frw3, frb3,
        fow1, fob1, fow2, fob2, fow3, fob3,
        fcw1, fcb1, fcw2, fcb2,
        (float*)d_out);
}